// Round 4
// baseline (88.785 us; speedup 1.0000x reference)
//
#include <hip/hip_runtime.h>
#include <math.h>

#define B_TOT 2048
#define T_N 6
#define V_N 100
#define P_N 20

// Kernel 1: ONE WAVE per batch element b; 256-thread blocks carry 4 b's
// (grid 512). No LDS, no barriers (R3's inter-wave handoff removed).
// Phase 1: lane l covers v=l (all lanes) and v=64+l (lanes 0..35). Per-t
//          min over points; cross-lane argmin via 64-bit lexicographic key
//          (sqrt_dist_bits<<32 | v) min-reduced with shfl_down — ties pick
//          the smaller v, matching jnp.argmin. sc<0.5 lanes skip the 160B
//          row load (halves HBM bytes).
// Phase 2: lanes 0..5 (t=lane): nearest point on chosen lane, yaws, wrap
//          chain, masks; wave shuffle-sum; lane 0 stores partial[b].
// No atomics (R1: 2048 same-address device atomicAdds cost ~22 us).
__global__ __launch_bounds__(256) void pmdl_kernel(
    const float* __restrict__ ego,    // [B, 6, 2]
    const float* __restrict__ lane,   // [B, 100, 20, 2] (raw, unscaled)
    const float* __restrict__ score,  // [B, 100, 3]
    float* __restrict__ partial)      // [B]
{
    const int wv = threadIdx.x >> 6;
    const int ln = threadIdx.x & 63;
    const int b  = blockIdx.x * 4 + wv;

    // ---- trajectory cumsum (wave-uniform address -> broadcast loads) ----
    const float* e = ego + (size_t)b * (T_N * 2);
    float px[T_N], py[T_N];
    {
        float cx = 0.f, cy = 0.f;
        #pragma unroll
        for (int t = 0; t < T_N; ++t) {
            cx += e[2 * t];
            cy += e[2 * t + 1];
            px[t] = cx; py[t] = cy;
        }
    }
    const float tdx = px[T_N - 1] - px[0];
    const float tdy = py[T_N - 1] - py[0];
    const bool static_mask = sqrtf(tdx * tdx + tdy * tdy) < 1.0f;

    // ---- phase 1: candidate A (v=ln) and candidate B (v=64+ln, ln<36) ----
    float mA2[T_N], mB2[T_N];
    {
        const float sc = score[((size_t)b * V_N + ln) * 3];
        if (sc < 0.5f) {
            #pragma unroll
            for (int t = 0; t < T_N; ++t) {
                float dx = px[t] - 1e6f, dy = py[t] - 1e6f;
                mA2[t] = fmaf(dx, dx, dy * dy);
            }
        } else {
            #pragma unroll
            for (int t = 0; t < T_N; ++t) mA2[t] = 3.0e38f;
            const float4* lp =
                (const float4*)(lane + ((size_t)b * V_N + ln) * (P_N * 2));
            #pragma unroll
            for (int j = 0; j < P_N / 2; ++j) {
                float4 q = lp[j];
                float x0 = fmaf(q.x, 30.f, -15.f);
                float y0 = fmaf(q.y, 60.f, -30.f);
                float x1 = fmaf(q.z, 30.f, -15.f);
                float y1 = fmaf(q.w, 60.f, -30.f);
                #pragma unroll
                for (int t = 0; t < T_N; ++t) {
                    float dx0 = px[t] - x0, dy0 = py[t] - y0;
                    float d0  = fmaf(dx0, dx0, dy0 * dy0);
                    float dx1 = px[t] - x1, dy1 = py[t] - y1;
                    float d1  = fmaf(dx1, dx1, dy1 * dy1);
                    mA2[t] = fminf(mA2[t], fminf(d0, d1));
                }
            }
        }
    }
    const bool hasB = ln < (V_N - 64);  // lanes 0..35 -> v = 64..99
    if (hasB) {
        const int v2 = 64 + ln;
        const float sc = score[((size_t)b * V_N + v2) * 3];
        if (sc < 0.5f) {
            #pragma unroll
            for (int t = 0; t < T_N; ++t) {
                float dx = px[t] - 1e6f, dy = py[t] - 1e6f;
                mB2[t] = fmaf(dx, dx, dy * dy);
            }
        } else {
            #pragma unroll
            for (int t = 0; t < T_N; ++t) mB2[t] = 3.0e38f;
            const float4* lp =
                (const float4*)(lane + ((size_t)b * V_N + v2) * (P_N * 2));
            #pragma unroll
            for (int j = 0; j < P_N / 2; ++j) {
                float4 q = lp[j];
                float x0 = fmaf(q.x, 30.f, -15.f);
                float y0 = fmaf(q.y, 60.f, -30.f);
                float x1 = fmaf(q.z, 30.f, -15.f);
                float y1 = fmaf(q.w, 60.f, -30.f);
                #pragma unroll
                for (int t = 0; t < T_N; ++t) {
                    float dx0 = px[t] - x0, dy0 = py[t] - y0;
                    float d0  = fmaf(dx0, dx0, dy0 * dy0);
                    float dx1 = px[t] - x1, dy1 = py[t] - y1;
                    float d1  = fmaf(dx1, dx1, dy1 * dy1);
                    mB2[t] = fminf(mB2[t], fminf(d0, d1));
                }
            }
        }
    }

    // ---- lexicographic (sqrt_dist, v) keys; sqrt once per (v,t) ----
    // min_p sqrtf(d2) == sqrtf(min_p d2) (sqrt monotone, correctly rounded);
    // ref argmins over sqrt'd values, so ties are compared post-sqrt. B's
    // key wins only if strictly smaller (equal dist -> smaller v = A).
    unsigned vsel_u = 0;
    #pragma unroll
    for (int t = 0; t < T_N; ++t) {
        unsigned long long k =
            ((unsigned long long)__float_as_uint(sqrtf(mA2[t])) << 32)
            | (unsigned)ln;
        if (hasB) {
            unsigned long long kB =
                ((unsigned long long)__float_as_uint(sqrtf(mB2[t])) << 32)
                | (unsigned)(64 + ln);
            if (kB < k) k = kB;
        }
        #pragma unroll
        for (int off = 32; off > 0; off >>= 1) {
            unsigned long long o = __shfl_down(k, off, 64);
            if (o < k) k = o;
        }
        k = __shfl(k, 0, 64);  // broadcast wave argmin
        if (ln == t) vsel_u = (unsigned)(k & 0xFFFFFFFFu);
    }

    // ---- phase 2: lanes 0..5 (t = ln) ----
    float loss = 0.f;
    if (ln < T_N) {
        // register-array reads with compile-time indices only (rule #20)
        float pxt = 0.f, pyt = 0.f, yawx = 0.f, yawy = 0.f;
        #pragma unroll
        for (int t = 0; t < T_N; ++t) {
            if (ln == t) {
                pxt = px[t]; pyt = py[t];
                yawx = (t < T_N - 1) ? (px[t + 1] - px[t])
                                     : (px[T_N - 1] - px[T_N - 2]);
                yawy = (t < T_N - 1) ? (py[t + 1] - py[t])
                                     : (py[T_N - 1] - py[T_N - 2]);
            }
        }
        const float sc = score[((size_t)b * V_N + vsel_u) * 3];
        const bool real = !(sc < 0.5f);  // false -> lane masked to 1e6
        const float* basep = lane + ((size_t)b * V_N + vsel_u) * (P_N * 2);

        // argmin over 20 points (strict '<' keeps first index)
        float best = 3.0e38f;
        int   bi   = 0;
        const float4* lp = (const float4*)basep;
        #pragma unroll
        for (int j = 0; j < P_N / 2; ++j) {
            float4 q = lp[j];
            float x0 = real ? fmaf(q.x, 30.f, -15.f) : 1e6f;
            float y0 = real ? fmaf(q.y, 60.f, -30.f) : 1e6f;
            float x1 = real ? fmaf(q.z, 30.f, -15.f) : 1e6f;
            float y1 = real ? fmaf(q.w, 60.f, -30.f) : 1e6f;
            float dx0 = x0 - pxt, dy0 = y0 - pyt;
            float d0  = sqrtf(fmaf(dx0, dx0, dy0 * dy0));
            float dx1 = x1 - pxt, dy1 = y1 - pyt;
            float d1  = sqrtf(fmaf(dx1, dx1, dy1 * dy1));
            if (d0 < best) { best = d0; bi = 2 * j; }
            if (d1 < best) { best = d1; bi = 2 * j + 1; }
        }
        const int ni = (bi == P_N - 1) ? P_N - 2 : bi + 1;

        // reload chosen points directly (no runtime-indexed reg arrays)
        const float2* lp2 = (const float2*)basep;
        float2 c2 = lp2[bi];
        float2 n2 = lp2[ni];
        float cxp = real ? fmaf(c2.x, 30.f, -15.f) : 1e6f;
        float cyp = real ? fmaf(c2.y, 60.f, -30.f) : 1e6f;
        float nxp = real ? fmaf(n2.x, 30.f, -15.f) : 1e6f;
        float nyp = real ? fmaf(n2.y, 60.f, -30.f) : 1e6f;

        float tyaw = atan2f(yawy, yawx);
        float lyaw = atan2f(nyp - cyp, nxp - cxp);

        float yd = tyaw - lyaw;
        const float PIf = 3.14159274101257324f;  // (float)math.pi
        if (yd >  PIf)        yd -= PIf;
        if (yd >  0.5f * PIf) yd -= PIf;
        if (yd < -PIf)        yd += PIf;
        if (yd < -0.5f * PIf) yd += PIf;
        if (best > 2.0f)  yd = 0.f;   // dist_mask
        if (static_mask)  yd = 0.f;
        loss = fabsf(yd);
    }
    // wave sum of lanes 0..5 (others contribute 0)
    #pragma unroll
    for (int off = 32; off > 0; off >>= 1)
        loss += __shfl_down(loss, off, 64);
    if (ln == 0) partial[b] = loss;   // 4 consecutive floats per block
}

// Kernel 2: single block reduces the 2048 partials and stores the mean.
__global__ __launch_bounds__(256) void pmdl_reduce(
    const float* __restrict__ partial,  // [B]
    float* __restrict__ out)            // [1]
{
    const int tid = threadIdx.x;
    float s = 0.f;
    #pragma unroll
    for (int i = 0; i < B_TOT / 256; ++i) s += partial[tid + i * 256];
    #pragma unroll
    for (int off = 32; off > 0; off >>= 1) s += __shfl_down(s, off, 64);
    __shared__ float wsum[4];
    if ((tid & 63) == 0) wsum[tid >> 6] = s;
    __syncthreads();
    if (tid == 0) {
        float tot = wsum[0] + wsum[1] + wsum[2] + wsum[3];
        out[0] = tot * (1.0f / (float)(B_TOT * T_N));
    }
}

extern "C" void kernel_launch(void* const* d_in, const int* in_sizes, int n_in,
                              void* d_out, int out_size, void* d_ws, size_t ws_size,
                              hipStream_t stream) {
    const float* ego   = (const float*)d_in[0];  // [2048,6,2]
    const float* lane  = (const float*)d_in[1];  // [2048,100,20,2]
    const float* score = (const float*)d_in[2];  // [2048,100,3]
    float* partialbuf = (float*)d_ws;            // 2048 floats, fully rewritten
    float* out        = (float*)d_out;

    pmdl_kernel<<<B_TOT / 4, 256, 0, stream>>>(ego, lane, score, partialbuf);
    pmdl_reduce<<<1, 256, 0, stream>>>(partialbuf, out);
}